// Round 13
// baseline (816.682 us; speedup 1.0000x reference)
//
#include <hip/hip_runtime.h>
#include <hip/hip_fp16.h>

// GCN 3-layer forward. R18 = R17 resubmitted unchanged (crash disambiguation:
// "Aborted (core dumped)" on an unhealthy node [803s npz push]; full audit of
// R17's new paths found no OOB/alignment/overflow — access pattern is a strict
// subset of R15's. If crash repeats -> real bug -> revert to R16.)
//  - segments allocated pad-to-4 (4-aligned starts) but GATHERED pad-to-2;
//    srcS read as int4 (4 idx/load) with tail guard. Gaps sentinel-filled.
//  - request ledger (2.3cy/lane-request, fits R15+R16 <3%): 41.6M vs 44.5M.

typedef unsigned int uint;
typedef unsigned short ushort;
typedef unsigned long long ull;

#define NBMAX 1024        // max buckets (dst >> 9), 512 nodes each
#define BKN 512
#define BCAP 17408        // bucketed slab cap per bucket (mean 16384, +8 sigma)
#define EPT 34            // bucketed entries per k_csr thread (BCAP/512)
#define SCAP 24576        // srcS slab cap (mean ~22.5k alloc, ~9 sigma)
#define PT_THREADS 512
#define PT_TILE 8192      // 16 edges per thread
#define NPART 8           // src partitions (src>>16): 2MB fp16 table slices
#define BAR_STRIDE 528    // uints per barrier row (root + 32 spread counters)
#define BAR_LAYER (7 * BAR_STRIDE)

// ---- init: fixed slab cursors + barrier counters ----
__global__ void k_init(uint* __restrict__ gcur, uint* __restrict__ bars) {
    int t = threadIdx.x;                 // 1024 threads, 1 block
    gcur[t] = (uint)t * BCAP;
    for (int i = t; i < 2 * BAR_LAYER; i += 1024) bars[i] = 0;
}

// ---- LDS-staged partition: edges -> bucketed (packed src | dstLocal<<19) ----
__global__ __launch_bounds__(PT_THREADS) void k_part(const int* __restrict__ src,
                                                     const int* __restrict__ dst, int E,
                                                     uint* __restrict__ gcur,
                                                     uint* __restrict__ bucketed) {
    __shared__ uint stage[PT_TILE];
    __shared__ ushort sbuck[PT_TILE];
    __shared__ uint hist[NBMAX], lofs[NBMAX], base[NBMAX];
    __shared__ uint tsum[PT_THREADS];
    int t = threadIdx.x;
    long long start = (long long)blockIdx.x * PT_TILE;
    int cnt = (int)min((long long)PT_TILE, (long long)E - start);

    hist[2 * t] = 0; hist[2 * t + 1] = 0;
    __syncthreads();
    uint myb[16], myr[16], mys[16];
#pragma unroll
    for (int k = 0; k < 16; ++k) {
        int idx = t + k * PT_THREADS;
        if (idx < cnt) {
            uint d = (uint)dst[start + idx];
            uint s = (uint)src[start + idx];
            uint b = d >> 9;
            myb[k] = b;
            mys[k] = s | ((d & 511u) << 19);
            myr[k] = atomicAdd(&hist[b], 1u);
        }
    }
    __syncthreads();
    uint h0 = hist[2 * t], h1 = hist[2 * t + 1];
    tsum[t] = h0 + h1;
    __syncthreads();
    for (int off = 1; off < PT_THREADS; off <<= 1) {
        uint x = (t >= off) ? tsum[t - off] : 0u;
        __syncthreads();
        tsum[t] += x;
        __syncthreads();
    }
    uint ex = tsum[t] - (h0 + h1);
    lofs[2 * t] = ex;
    lofs[2 * t + 1] = ex + h0;
    if (h0) base[2 * t] = atomicAdd(&gcur[2 * t], h0);
    if (h1) base[2 * t + 1] = atomicAdd(&gcur[2 * t + 1], h1);
    __syncthreads();
#pragma unroll
    for (int k = 0; k < 16; ++k) {
        int idx = t + k * PT_THREADS;
        if (idx < cnt) {
            uint pos = lofs[myb[k]] + myr[k];
            stage[pos] = mys[k];
            sbuck[pos] = (ushort)myb[k];
        }
    }
    __syncthreads();
#pragma unroll
    for (int k = 0; k < 16; ++k) {
        int idx = t + k * PT_THREADS;
        if (idx < cnt) {
            uint b = sbuck[idx];
            uint pos = base[b] + ((uint)idx - lofs[b]);
            if (pos < (uint)(b + 1) * BCAP) bucketed[pos] = stage[idx];  // ~always
        }
    }
}

// ---- per-bucket CSR (counting sort; alloc pad-4, gather pad-2) + fused lin1 ----
// rowp8[(p<<19)+node] = (slabStart+segStart) | (cnt<<25); pads = sentinel N.
__global__ __launch_bounds__(512) void k_csr(const uint* __restrict__ bucketed,
                                             const uint* __restrict__ gcur,
                                             uint* __restrict__ rowp8,
                                             float* __restrict__ dis,
                                             int* __restrict__ srcS,
                                             const float* __restrict__ x,
                                             const float* __restrict__ W1,
                                             __half* __restrict__ Ap, int N) {
    __shared__ uint c[BKN * NPART];        // counts -> cursors (reused)
    __shared__ uint tsum[512];
    __shared__ __align__(16) int stage[SCAP];
    int b = blockIdx.x, t = threadIdx.x;
    uint beg = (uint)b * BCAP;
    uint end = min(gcur[b], (uint)(b + 1) * BCAP);
    for (int i = t; i < BKN * NPART; i += 512) c[i] = 0;
    __syncthreads();
    uint reg[EPT];                         // static-indexed (full unroll) -> VGPRs
#pragma unroll
    for (int i = 0; i < EPT; ++i) {
        uint e = beg + (uint)t + (uint)i * 512u;
        bool ok = e < end;
        uint v = ok ? bucketed[e] : 0u;
        reg[i] = ok ? v : 0xffffffffu;     // sentinel = skip
        if (ok) {
            uint key = (((v & 0x7ffffu) >> 16) << 9) | (v >> 19);
            atomicAdd(&c[key], 1u);
        }
    }
    __syncthreads();
    // degree -> dis (before counts become cursors); keep dival live for lin tail
    int node = (b << 9) + t;
    float dival = 0.f;
    if (node < N) {
        uint deg = 0;
#pragma unroll
        for (int p = 0; p < NPART; ++p) deg += c[(p << 9) | t];
        dival = rsqrtf((float)(deg + 1u));   // +1 self-loop
        dis[node] = dival;
    }
    // thread t owns keys 8t..8t+7 (one partition p=t>>6, 8 consecutive locals)
    uint cnt[8], pad[8], ps = 0;
#pragma unroll
    for (int i = 0; i < 8; ++i) {
        cnt[i] = c[t * 8 + i];
        pad[i] = (cnt[i] + 3u) & ~3u;       // ALLOC pad-4 (4-aligned starts)
        ps += pad[i];
    }
    __syncthreads();
    tsum[t] = ps;
    __syncthreads();
    for (int off = 1; off < 512; off <<= 1) {
        uint xv = (t >= off) ? tsum[t - off] : 0u;
        __syncthreads();
        tsum[t] += xv;
        __syncthreads();
    }
    uint tot = tsum[511];
    uint kb = tsum[t] - ps;
    uint slab = (uint)b * SCAP;
    int p = t >> 6, local0 = (t & 63) << 3;
    uint run = kb;
#pragma unroll
    for (int i = 0; i < 8; ++i) {
        uint st = run;
        rowp8[((uint)p << 19) + (uint)((b << 9) + local0 + i)] =
            (slab + st) | (cnt[i] << 25);
        c[t * 8 + i] = st;                  // cursor, slab-relative
        for (uint q = cnt[i]; q < pad[i]; ++q) {   // sentinel pads+gaps (<=3)
            uint idx = st + q;
            if (idx < (uint)SCAP) stage[idx] = N;
            else srcS[slab + idx] = N;      // ~never (spill)
        }
        run += pad[i];
    }
    __syncthreads();
#pragma unroll
    for (int i = 0; i < EPT; ++i) {
        uint v = reg[i];
        if (v != 0xffffffffu) {
            uint s = v & 0x7ffffu;
            uint key = ((s >> 16) << 9) | (v >> 19);
            uint idx = atomicAdd(&c[key], 1u);
            if (idx < (uint)SCAP) stage[idx] = (int)s;
            else srcS[slab + idx] = (int)s; // ~never (spill)
        }
    }
    __syncthreads();
    uint capped = min(tot, (uint)SCAP);
    uint cap4 = capped & ~3u;
    for (uint i = t * 4; i < cap4; i += 512 * 4)
        *(int4*)(srcS + slab + i) = *(const int4*)(stage + i);
    if (t < (int)(capped & 3u)) srcS[slab + cap4 + t] = stage[cap4 + t];
    // ---- fused layer-1 linear (no LDS deps; W1 reads are wave-uniform) ----
    if (node < N) {
        float in[15];
#pragma unroll
        for (int j = 0; j < 15; ++j) in[j] = x[(size_t)node * 15 + j];
        float o[16];
        o[15] = 0.f;
#pragma unroll
        for (int oj = 0; oj < 15; ++oj) {
            float acc = 0.f;
#pragma unroll
            for (int j = 0; j < 15; ++j) acc = fmaf(in[j], W1[j * 15 + oj], acc);
            o[oj] = acc * dival;
        }
        __half2 ob[8];
#pragma unroll
        for (int j = 0; j < 8; ++j)
            ob[j] = __floats2half2_rn(o[2 * j], o[2 * j + 1]);
        *(int4*)(Ap + (size_t)node * 16) = *(int4*)&ob[0];
        *(int4*)(Ap + (size_t)node * 16 + 8) = *(int4*)&ob[4];
    }
}

// ---- soft global barrier: locality pacing only (no correctness dependence) ----
__device__ __forceinline__ void softbar(uint* __restrict__ bars, int phase, int nblk) {
    __syncthreads();
    if (threadIdx.x == 0) {
        uint* row = bars + phase * BAR_STRIDE;
        uint ngroups = ((uint)nblk + 31u) >> 5;
        uint g = (uint)blockIdx.x >> 5;
        uint gsz = min(32u, (uint)nblk - g * 32u);
        uint prev = atomicAdd(&row[16 + g * 16], 1u);   // spread counters, own line
        if (prev + 1u == gsz) atomicAdd(&row[0], 1u);
        int spins = 0;
        while (spins < 2000) {
            uint v = __hip_atomic_load(&row[0], __ATOMIC_RELAXED,
                                       __HIP_MEMORY_SCOPE_AGENT);
            if (v >= ngroups) break;
            __builtin_amdgcn_s_sleep(8);
            ++spins;
        }
    }
    __syncthreads();
}

template <int TW>
__device__ __forceinline__ void load_row(const __half* __restrict__ tab, int node,
                                         float (&acc)[TW]) {
    if constexpr (TW == 16) {
        int4 w0 = *(const int4*)(tab + (size_t)node * 16);
        int4 w1 = *(const int4*)(tab + (size_t)node * 16 + 8);
        const __half2* h0 = (const __half2*)&w0;
        const __half2* h1 = (const __half2*)&w1;
#pragma unroll
        for (int u = 0; u < 4; ++u) {
            float2 f0 = __half22float2(h0[u]);
            float2 f1 = __half22float2(h1[u]);
            acc[2 * u] = f0.x;
            acc[2 * u + 1] = f0.y;
            acc[8 + 2 * u] = f1.x;
            acc[8 + 2 * u + 1] = f1.y;
        }
    } else {
        int2 w = *(const int2*)(tab + (size_t)node * 4);
        const __half2* h = (const __half2*)&w;
        float2 f0 = __half22float2(h[0]);
        float2 f1 = __half22float2(h[1]);
        acc[0] = f0.x; acc[1] = f0.y; acc[2] = f1.x; acc[3] = f1.y;
    }
}

// accumulate one row pair (32B rows: 4x dwordx4; 8B rows: 2x dwordx2)
template <int TW>
__device__ __forceinline__ void acc_pair(const __half* __restrict__ tab,
                                         int s0, int s1, float (&acc)[TW]) {
    if constexpr (TW == 16) {
        const int4* p0 = (const int4*)(tab + (size_t)s0 * 16);
        const int4* p1 = (const int4*)(tab + (size_t)s1 * 16);
        int4 r[4];
        r[0] = p0[0]; r[1] = p1[0]; r[2] = p0[1]; r[3] = p1[1];
#pragma unroll
        for (int q = 0; q < 4; ++q) {
            const __half2* h2 = (const __half2*)&r[q];
            int base = (q >> 1) * 8;        // r[0..1] -> lo half, r[2..3] -> hi
#pragma unroll
            for (int u = 0; u < 4; ++u) {
                float2 f = __half22float2(h2[u]);
                acc[base + 2 * u] += f.x;
                acc[base + 2 * u + 1] += f.y;
            }
        }
    } else {                                // TW == 4
        int2 r0 = *(const int2*)(tab + (size_t)s0 * 4);
        int2 r1 = *(const int2*)(tab + (size_t)s1 * 4);
        const __half2* h0 = (const __half2*)&r0;
        const __half2* h1 = (const __half2*)&r1;
#pragma unroll
        for (int u = 0; u < 2; ++u) {
            float2 f0 = __half22float2(h0[u]);
            float2 f1 = __half22float2(h1[u]);
            acc[2 * u] += f0.x + f1.x;
            acc[2 * u + 1] += f0.y + f1.y;
        }
    }
}

// gather: int4 srcS loads (4 idx), gather pad-2 rows, tail guard skips pair1
template <int TW>
__device__ __forceinline__ void gather_seg(const __half* __restrict__ tab,
                                           const int* __restrict__ srcS,
                                           uint rv, float (&acc)[TW]) {
    uint cnt = rv >> 25;
    if (!cnt) return;
    uint e = rv & 0x1ffffffu;               // 4-aligned (alloc pad-4)
    uint len2 = (cnt + 1u) & ~1u;           // gathered length (pad-2)
    for (uint off = 0; off < len2; off += 4) {
        int4 s4 = *(const int4*)(srcS + e + off);
        acc_pair<TW>(tab, s4.x, s4.y, acc);
        if (off + 2u < len2) acc_pair<TW>(tab, s4.z, s4.w, acc);
    }
}

// ---- resident phased pull: thread owns 2 nodes, register acc, 8 phases ----
// L=1: Ap->relu@W2->Bp  L=2: Bp->relu@W3->Cp  L=3: Cp->out fp32 (no softbar)
template <int L>
__global__ __launch_bounds__(512, 4) void k_pull_res(
    const __half* __restrict__ tab, const int* __restrict__ srcS,
    const uint* __restrict__ rowp8, const float* __restrict__ dis,
    const float* __restrict__ Wm, const float* __restrict__ bias,
    void* __restrict__ outp, uint* __restrict__ bars, int nblk, int N) {
    constexpr int TW = (L == 3) ? 4 : 16;
    __shared__ float wl[240];
    int t = threadIdx.x;
    int n0 = (blockIdx.x << 10) + t;
    int n1 = n0 + 512;
    if constexpr (L == 1) {
        for (int i = t; i < 225; i += 512) wl[i] = Wm[i];
        if (t < 15) wl[225 + t] = bias[t];
    }
    if constexpr (L == 2) {
        for (int i = t; i < 60; i += 512) wl[i] = Wm[i];
        if (t < 15) wl[60 + t] = bias[t];
    }
    if constexpr (L == 3) {
        if (t < 4) wl[t] = bias[t];
    }
    __syncthreads();
    bool v0 = n0 < N, v1 = n1 < N;
    float a0[TW], a1[TW];
    if (v0) load_row<TW>(tab, n0, a0);
    if (v1) load_row<TW>(tab, n1, a1);
    uint rv0 = v0 ? rowp8[(uint)n0] : 0u;      // phase-0 descriptors
    uint rv1 = v1 ? rowp8[(uint)n1] : 0u;
    for (int p = 0; p < NPART; ++p) {
        uint nv0 = 0u, nv1 = 0u;
        if (p < NPART - 1) {                   // prefetch next phase descriptors
            uint pb = (uint)(p + 1) << 19;
            if (v0) nv0 = rowp8[pb + (uint)n0];
            if (v1) nv1 = rowp8[pb + (uint)n1];
        }
        if (v0) gather_seg<TW>(tab, srcS, rv0, a0);
        if (v1) gather_seg<TW>(tab, srcS, rv1, a1);
        if constexpr (L != 3) {                // pull3: 4MB table, locality moot
            if (p < NPART - 1) softbar(bars, p, nblk);
        }
        rv0 = nv0; rv1 = nv1;
    }
    // epilogue (per node, all-register MLP)
#pragma unroll
    for (int nn = 0; nn < 2; ++nn) {
        int node = nn ? n1 : n0;
        if (node >= N) continue;
        float* a = nn ? a1 : a0;
        float di = dis[node];
        if constexpr (L == 3) {
            float4 o;
            o.x = a[0] * di + wl[0];
            o.y = a[1] * di + wl[1];
            o.z = a[2] * di + wl[2];
            o.w = a[3] * di + wl[3];
            *(float4*)((float*)outp + (size_t)node * 4) = o;
        } else {
            float h[15];
#pragma unroll
            for (int j = 0; j < 15; ++j) {
                float bj = (L == 1) ? wl[225 + j] : wl[60 + j];
                h[j] = fmaxf(a[j] * di + bj, 0.f);
            }
            if constexpr (L == 1) {
                float o[16];
                o[15] = 0.f;
#pragma unroll
                for (int j = 0; j < 15; ++j) {
                    float s = 0.f;
#pragma unroll
                    for (int k = 0; k < 15; ++k) s = fmaf(h[k], wl[k * 15 + j], s);
                    o[j] = s * di;
                }
                __half2 ob[8];
#pragma unroll
                for (int j = 0; j < 8; ++j)
                    ob[j] = __floats2half2_rn(o[2 * j], o[2 * j + 1]);
                *(int4*)((__half*)outp + (size_t)node * 16) = *(int4*)&ob[0];
                *(int4*)((__half*)outp + (size_t)node * 16 + 8) = *(int4*)&ob[4];
            } else {
                float o[4];
#pragma unroll
                for (int j = 0; j < 4; ++j) {
                    float s = 0.f;
#pragma unroll
                    for (int k = 0; k < 15; ++k) s = fmaf(h[k], wl[k * 4 + j], s);
                    o[j] = s * di;
                }
                __half2 ob[2];
                ob[0] = __floats2half2_rn(o[0], o[1]);
                ob[1] = __floats2half2_rn(o[2], o[3]);
                *(float2*)((__half*)outp + (size_t)node * 4) = *(float2*)&ob[0];
            }
        }
    }
}

extern "C" void kernel_launch(void* const* d_in, const int* in_sizes, int n_in,
                              void* d_out, int out_size, void* d_ws, size_t ws_size,
                              hipStream_t stream) {
    const float* x  = (const float*)d_in[0];
    const int*   ei = (const int*)d_in[1];
    const float* W1 = (const float*)d_in[3];
    const float* b1 = (const float*)d_in[4];
    const float* W2 = (const float*)d_in[5];
    const float* b2 = (const float*)d_in[6];
    const float* W3 = (const float*)d_in[7];
    const float* b3 = (const float*)d_in[8];
    float* out = (float*)d_out;

    const int N = in_sizes[0] / 15;
    const int E = in_sizes[1] / 2;
    const int* src = ei;
    const int* dst = ei + E;
    const int NBr = (N + BKN - 1) / BKN;   // live buckets (977)
    const int PB  = (NBr + 1) / 2;         // pull blocks (489)

    char* ws = (char*)d_ws;
    auto align = [](size_t v) { return (v + 255) & ~(size_t)255; };
    size_t off = 0;
    uint* rowp8 = (uint*)(ws + off); off += align((size_t)NPART * (1u << 19) * 4);
    float* dis  = (float*)(ws + off); off += align((size_t)N * 4);
    uint* gcur  = (uint*)(ws + off); off += align((size_t)NBMAX * 4);
    uint* bars  = (uint*)(ws + off); off += align((size_t)2 * BAR_LAYER * 4);
    int*  srcS  = (int*)(ws + off);  off += align((size_t)NBMAX * SCAP * 4);
    // slabY: bucketed (71MB) dead after k_csr, overlaid by B'(fp16)+C'(fp16)
    char* slabY = ws + off;
    uint*   bucketed = (uint*)slabY;
    __half* Bp = (__half*)slabY;
    __half* Cp = (__half*)(slabY + align((size_t)(N + 1) * 16 * 2));
    off += align((size_t)NBMAX * BCAP * 4);
    __half* Ap = (__half*)(ws + off);  // (N+1) x 16 fp16

    const int nTiles = (E + PT_TILE - 1) / PT_TILE;

    // CSR build (partition-major rows, fixed slabs) + fused layer-1 linear
    k_init<<<1, 1024, 0, stream>>>(gcur, bars);
    k_part<<<nTiles, PT_THREADS, 0, stream>>>(src, dst, E, gcur, bucketed);
    k_csr<<<NBr, 512, 0, stream>>>(bucketed, gcur, rowp8, dis, srcS, x, W1, Ap, N);
    // bucketed dead -> slabY becomes B'/C'

    // sentinel zero-rows (row N) for pad gathers
    hipMemsetAsync(Ap + (size_t)N * 16, 0, 16 * 2, stream);
    hipMemsetAsync(Bp + (size_t)N * 16, 0, 16 * 2, stream);
    hipMemsetAsync(Cp + (size_t)N * 4, 0, 4 * 2, stream);

    k_pull_res<1><<<PB, 512, 0, stream>>>(Ap, srcS, rowp8, dis, W2, b1, Bp,
                                          bars + 0 * BAR_LAYER, PB, N);
    k_pull_res<2><<<PB, 512, 0, stream>>>(Bp, srcS, rowp8, dis, W3, b2, Cp,
                                          bars + 1 * BAR_LAYER, PB, N);
    k_pull_res<3><<<PB, 512, 0, stream>>>(Cp, srcS, rowp8, dis, nullptr, b3, out,
                                          nullptr, PB, N);
}

// Round 14
// 787.994 us; speedup vs baseline: 1.0364x; 1.0364x over previous
//
#include <hip/hip_runtime.h>
#include <hip/hip_fp16.h>

// GCN 3-layer forward. R19 = exact R16 revert (best: 786us; R18's int4-srcS
// regressed to 816) + k_csr fill-pass atomic elimination:
//  - histogram atomicAdd's return value IS the entry's within-key rank;
//    cache it (ushort rk[EPT], static-indexed -> VGPR) and fill becomes
//    stage[c[key]+rk[i]] -- no 2nd 16M LDS-atomic pass.
// Pulls CLOSED: 5 falsifications (occupancy/vectorize/pairing/int4/pad-alloc)
// around R16's optimum (pad2 alloc+gather, ull srcS, 169.5us each).

typedef unsigned int uint;
typedef unsigned short ushort;
typedef unsigned long long ull;

#define NBMAX 1024        // max buckets (dst >> 9), 512 nodes each
#define BKN 512
#define BCAP 17408        // bucketed slab cap per bucket (mean 16384, +8 sigma)
#define EPT 34            // bucketed entries per k_csr thread (BCAP/512)
#define SCAP 24576        // srcS slab cap (mean ~18.4k padded, huge headroom)
#define PT_THREADS 512
#define PT_TILE 8192      // 16 edges per thread
#define NPART 8           // src partitions (src>>16): 2MB fp16 table slices
#define BAR_STRIDE 528    // uints per barrier row (root + 32 spread counters)
#define BAR_LAYER (7 * BAR_STRIDE)

// ---- init: fixed slab cursors + barrier counters ----
__global__ void k_init(uint* __restrict__ gcur, uint* __restrict__ bars) {
    int t = threadIdx.x;                 // 1024 threads, 1 block
    gcur[t] = (uint)t * BCAP;
    for (int i = t; i < 2 * BAR_LAYER; i += 1024) bars[i] = 0;
}

// ---- LDS-staged partition: edges -> bucketed (packed src | dstLocal<<19) ----
__global__ __launch_bounds__(PT_THREADS) void k_part(const int* __restrict__ src,
                                                     const int* __restrict__ dst, int E,
                                                     uint* __restrict__ gcur,
                                                     uint* __restrict__ bucketed) {
    __shared__ uint stage[PT_TILE];
    __shared__ ushort sbuck[PT_TILE];
    __shared__ uint hist[NBMAX], lofs[NBMAX], base[NBMAX];
    __shared__ uint tsum[PT_THREADS];
    int t = threadIdx.x;
    long long start = (long long)blockIdx.x * PT_TILE;
    int cnt = (int)min((long long)PT_TILE, (long long)E - start);

    hist[2 * t] = 0; hist[2 * t + 1] = 0;
    __syncthreads();
    uint myb[16], myr[16], mys[16];
#pragma unroll
    for (int k = 0; k < 16; ++k) {
        int idx = t + k * PT_THREADS;
        if (idx < cnt) {
            uint d = (uint)dst[start + idx];
            uint s = (uint)src[start + idx];
            uint b = d >> 9;
            myb[k] = b;
            mys[k] = s | ((d & 511u) << 19);
            myr[k] = atomicAdd(&hist[b], 1u);
        }
    }
    __syncthreads();
    uint h0 = hist[2 * t], h1 = hist[2 * t + 1];
    tsum[t] = h0 + h1;
    __syncthreads();
    for (int off = 1; off < PT_THREADS; off <<= 1) {
        uint x = (t >= off) ? tsum[t - off] : 0u;
        __syncthreads();
        tsum[t] += x;
        __syncthreads();
    }
    uint ex = tsum[t] - (h0 + h1);
    lofs[2 * t] = ex;
    lofs[2 * t + 1] = ex + h0;
    if (h0) base[2 * t] = atomicAdd(&gcur[2 * t], h0);
    if (h1) base[2 * t + 1] = atomicAdd(&gcur[2 * t + 1], h1);
    __syncthreads();
#pragma unroll
    for (int k = 0; k < 16; ++k) {
        int idx = t + k * PT_THREADS;
        if (idx < cnt) {
            uint pos = lofs[myb[k]] + myr[k];
            stage[pos] = mys[k];
            sbuck[pos] = (ushort)myb[k];
        }
    }
    __syncthreads();
#pragma unroll
    for (int k = 0; k < 16; ++k) {
        int idx = t + k * PT_THREADS;
        if (idx < cnt) {
            uint b = sbuck[idx];
            uint pos = base[b] + ((uint)idx - lofs[b]);
            if (pos < (uint)(b + 1) * BCAP) bucketed[pos] = stage[idx];  // ~always
        }
    }
}

// ---- per-bucket CSR (counting sort, pad-to-2) + fused layer-1 linear ----
// rowp8[(p<<19)+node] = (slabStart+segStart) | (cnt<<25); pad slots = sentinel N.
// R19: fill pass uses rank cached from histogram pass -> no 2nd LDS atomic.
__global__ __launch_bounds__(512) void k_csr(const uint* __restrict__ bucketed,
                                             const uint* __restrict__ gcur,
                                             uint* __restrict__ rowp8,
                                             float* __restrict__ dis,
                                             int* __restrict__ srcS,
                                             const float* __restrict__ x,
                                             const float* __restrict__ W1,
                                             __half* __restrict__ Ap, int N) {
    __shared__ uint c[BKN * NPART];        // counts -> cursors (reused)
    __shared__ uint tsum[512];
    __shared__ __align__(16) int stage[SCAP];
    int b = blockIdx.x, t = threadIdx.x;
    uint beg = (uint)b * BCAP;
    uint end = min(gcur[b], (uint)(b + 1) * BCAP);
    for (int i = t; i < BKN * NPART; i += 512) c[i] = 0;
    __syncthreads();
    uint reg[EPT];                         // static-indexed (full unroll) -> VGPRs
    ushort rk[EPT];                        // within-key rank from histogram pass
#pragma unroll
    for (int i = 0; i < EPT; ++i) {
        uint e = beg + (uint)t + (uint)i * 512u;
        bool ok = e < end;
        uint v = ok ? bucketed[e] : 0u;
        reg[i] = ok ? v : 0xffffffffu;     // sentinel = skip
        rk[i] = 0;
        if (ok) {
            uint key = (((v & 0x7ffffu) >> 16) << 9) | (v >> 19);
            rk[i] = (ushort)atomicAdd(&c[key], 1u);
        }
    }
    __syncthreads();
    // degree -> dis (before counts become cursors); keep dival live for lin tail
    int node = (b << 9) + t;
    float dival = 0.f;
    if (node < N) {
        uint deg = 0;
#pragma unroll
        for (int p = 0; p < NPART; ++p) deg += c[(p << 9) | t];
        dival = rsqrtf((float)(deg + 1u));   // +1 self-loop
        dis[node] = dival;
    }
    // thread t owns keys 8t..8t+7 (one partition p=t>>6, 8 consecutive locals)
    uint cnt[8], pad[8], ps = 0;
#pragma unroll
    for (int i = 0; i < 8; ++i) {
        cnt[i] = c[t * 8 + i];
        pad[i] = (cnt[i] + 1u) & ~1u;       // pad-to-2
        ps += pad[i];
    }
    __syncthreads();
    tsum[t] = ps;
    __syncthreads();
    for (int off = 1; off < 512; off <<= 1) {
        uint xv = (t >= off) ? tsum[t - off] : 0u;
        __syncthreads();
        tsum[t] += xv;
        __syncthreads();
    }
    uint tot = tsum[511];
    uint kb = tsum[t] - ps;
    uint slab = (uint)b * SCAP;
    int p = t >> 6, local0 = (t & 63) << 3;
    uint run = kb;
#pragma unroll
    for (int i = 0; i < 8; ++i) {
        uint st = run;
        rowp8[((uint)p << 19) + (uint)((b << 9) + local0 + i)] =
            (slab + st) | (cnt[i] << 25);
        c[t * 8 + i] = st;                  // segment start (no atomics in fill)
        if (cnt[i] & 1u) {                  // sentinel pad (<=1)
            uint idx = st + cnt[i];
            if (idx < (uint)SCAP) stage[idx] = N;
            else srcS[slab + idx] = N;      // ~never (spill)
        }
        run += pad[i];
    }
    __syncthreads();
#pragma unroll
    for (int i = 0; i < EPT; ++i) {
        uint v = reg[i];
        if (v != 0xffffffffu) {
            uint s = v & 0x7ffffu;
            uint key = ((s >> 16) << 9) | (v >> 19);
            uint idx = c[key] + (uint)rk[i];   // base + cached rank, atomic-free
            if (idx < (uint)SCAP) stage[idx] = (int)s;
            else srcS[slab + idx] = (int)s;    // ~never (spill)
        }
    }
    __syncthreads();
    uint capped = min(tot, (uint)SCAP);
    uint cap4 = capped & ~3u;
    for (uint i = t * 4; i < cap4; i += 512 * 4)
        *(int4*)(srcS + slab + i) = *(const int4*)(stage + i);
    if (t < (int)(capped & 3u)) srcS[slab + cap4 + t] = stage[cap4 + t];
    // ---- fused layer-1 linear (no LDS deps; W1 reads are wave-uniform) ----
    if (node < N) {
        float in[15];
#pragma unroll
        for (int j = 0; j < 15; ++j) in[j] = x[(size_t)node * 15 + j];
        float o[16];
        o[15] = 0.f;
#pragma unroll
        for (int oj = 0; oj < 15; ++oj) {
            float acc = 0.f;
#pragma unroll
            for (int j = 0; j < 15; ++j) acc = fmaf(in[j], W1[j * 15 + oj], acc);
            o[oj] = acc * dival;
        }
        __half2 ob[8];
#pragma unroll
        for (int j = 0; j < 8; ++j)
            ob[j] = __floats2half2_rn(o[2 * j], o[2 * j + 1]);
        *(int4*)(Ap + (size_t)node * 16) = *(int4*)&ob[0];
        *(int4*)(Ap + (size_t)node * 16 + 8) = *(int4*)&ob[4];
    }
}

// ---- soft global barrier: locality pacing only (no correctness dependence) ----
__device__ __forceinline__ void softbar(uint* __restrict__ bars, int phase, int nblk) {
    __syncthreads();
    if (threadIdx.x == 0) {
        uint* row = bars + phase * BAR_STRIDE;
        uint ngroups = ((uint)nblk + 31u) >> 5;
        uint g = (uint)blockIdx.x >> 5;
        uint gsz = min(32u, (uint)nblk - g * 32u);
        uint prev = atomicAdd(&row[16 + g * 16], 1u);   // spread counters, own line
        if (prev + 1u == gsz) atomicAdd(&row[0], 1u);
        int spins = 0;
        while (spins < 2000) {
            uint v = __hip_atomic_load(&row[0], __ATOMIC_RELAXED,
                                       __HIP_MEMORY_SCOPE_AGENT);
            if (v >= ngroups) break;
            __builtin_amdgcn_s_sleep(8);
            ++spins;
        }
    }
    __syncthreads();
}

template <int TW>
__device__ __forceinline__ void load_row(const __half* __restrict__ tab, int node,
                                         float (&acc)[TW]) {
    if constexpr (TW == 16) {
        int4 w0 = *(const int4*)(tab + (size_t)node * 16);
        int4 w1 = *(const int4*)(tab + (size_t)node * 16 + 8);
        const __half2* h0 = (const __half2*)&w0;
        const __half2* h1 = (const __half2*)&w1;
#pragma unroll
        for (int u = 0; u < 4; ++u) {
            float2 f0 = __half22float2(h0[u]);
            float2 f1 = __half22float2(h1[u]);
            acc[2 * u] = f0.x;
            acc[2 * u + 1] = f0.y;
            acc[8 + 2 * u] = f1.x;
            acc[8 + 2 * u + 1] = f1.y;
        }
    } else {
        int2 w = *(const int2*)(tab + (size_t)node * 4);
        const __half2* h = (const __half2*)&w;
        float2 f0 = __half22float2(h[0]);
        float2 f1 = __half22float2(h[1]);
        acc[0] = f0.x; acc[1] = f0.y; acc[2] = f1.x; acc[3] = f1.y;
    }
}

// gather, 2 rows per iter (pad-to-2): 32B rows as 2x dwordx4, 8B as dwordx2
template <int TW>
__device__ __forceinline__ void gather_seg(const __half* __restrict__ tab,
                                           const int* __restrict__ srcS,
                                           uint rv, float (&acc)[TW]) {
    uint cnt = rv >> 25;
    if (!cnt) return;
    uint e = rv & 0x1ffffffu;
    uint end2 = e + ((cnt + 1u) & ~1u);
    for (; e < end2; e += 2) {
        ull w = *(const ull*)(srcS + e);        // 8B-aligned segment
        int s0 = (int)(uint)(w & 0xffffffffull);
        int s1 = (int)(uint)(w >> 32);
        if constexpr (TW == 16) {
            const int4* p0 = (const int4*)(tab + (size_t)s0 * 16);
            const int4* p1 = (const int4*)(tab + (size_t)s1 * 16);
            int4 r[4];
            r[0] = p0[0]; r[1] = p1[0]; r[2] = p0[1]; r[3] = p1[1];
#pragma unroll
            for (int q = 0; q < 4; ++q) {
                const __half2* h2 = (const __half2*)&r[q];
                int base = (q >> 1) * 8;        // r[0..1] -> lo half, r[2..3] -> hi
#pragma unroll
                for (int u = 0; u < 4; ++u) {
                    float2 f = __half22float2(h2[u]);
                    acc[base + 2 * u] += f.x;
                    acc[base + 2 * u + 1] += f.y;
                }
            }
        } else {                                // TW == 4
            int2 r0 = *(const int2*)(tab + (size_t)s0 * 4);
            int2 r1 = *(const int2*)(tab + (size_t)s1 * 4);
            const __half2* h0 = (const __half2*)&r0;
            const __half2* h1 = (const __half2*)&r1;
#pragma unroll
            for (int u = 0; u < 2; ++u) {
                float2 f0 = __half22float2(h0[u]);
                float2 f1 = __half22float2(h1[u]);
                acc[2 * u] += f0.x + f1.x;
                acc[2 * u + 1] += f0.y + f1.y;
            }
        }
    }
}

// ---- resident phased pull: thread owns 2 nodes, register acc, 8 phases ----
// L=1: Ap->relu@W2->Bp  L=2: Bp->relu@W3->Cp  L=3: Cp->out fp32 (no softbar)
template <int L>
__global__ __launch_bounds__(512, 4) void k_pull_res(
    const __half* __restrict__ tab, const int* __restrict__ srcS,
    const uint* __restrict__ rowp8, const float* __restrict__ dis,
    const float* __restrict__ Wm, const float* __restrict__ bias,
    void* __restrict__ outp, uint* __restrict__ bars, int nblk, int N) {
    constexpr int TW = (L == 3) ? 4 : 16;
    __shared__ float wl[240];
    int t = threadIdx.x;
    int n0 = (blockIdx.x << 10) + t;
    int n1 = n0 + 512;
    if constexpr (L == 1) {
        for (int i = t; i < 225; i += 512) wl[i] = Wm[i];
        if (t < 15) wl[225 + t] = bias[t];
    }
    if constexpr (L == 2) {
        for (int i = t; i < 60; i += 512) wl[i] = Wm[i];
        if (t < 15) wl[60 + t] = bias[t];
    }
    if constexpr (L == 3) {
        if (t < 4) wl[t] = bias[t];
    }
    __syncthreads();
    bool v0 = n0 < N, v1 = n1 < N;
    float a0[TW], a1[TW];
    if (v0) load_row<TW>(tab, n0, a0);
    if (v1) load_row<TW>(tab, n1, a1);
    uint rv0 = v0 ? rowp8[(uint)n0] : 0u;      // phase-0 descriptors
    uint rv1 = v1 ? rowp8[(uint)n1] : 0u;
    for (int p = 0; p < NPART; ++p) {
        uint nv0 = 0u, nv1 = 0u;
        if (p < NPART - 1) {                   // prefetch next phase descriptors
            uint pb = (uint)(p + 1) << 19;
            if (v0) nv0 = rowp8[pb + (uint)n0];
            if (v1) nv1 = rowp8[pb + (uint)n1];
        }
        if (v0) gather_seg<TW>(tab, srcS, rv0, a0);
        if (v1) gather_seg<TW>(tab, srcS, rv1, a1);
        if constexpr (L != 3) {                // pull3: 4MB table, locality moot
            if (p < NPART - 1) softbar(bars, p, nblk);
        }
        rv0 = nv0; rv1 = nv1;
    }
    // epilogue (per node, all-register MLP)
#pragma unroll
    for (int nn = 0; nn < 2; ++nn) {
        int node = nn ? n1 : n0;
        if (node >= N) continue;
        float* a = nn ? a1 : a0;
        float di = dis[node];
        if constexpr (L == 3) {
            float4 o;
            o.x = a[0] * di + wl[0];
            o.y = a[1] * di + wl[1];
            o.z = a[2] * di + wl[2];
            o.w = a[3] * di + wl[3];
            *(float4*)((float*)outp + (size_t)node * 4) = o;
        } else {
            float h[15];
#pragma unroll
            for (int j = 0; j < 15; ++j) {
                float bj = (L == 1) ? wl[225 + j] : wl[60 + j];
                h[j] = fmaxf(a[j] * di + bj, 0.f);
            }
            if constexpr (L == 1) {
                float o[16];
                o[15] = 0.f;
#pragma unroll
                for (int j = 0; j < 15; ++j) {
                    float s = 0.f;
#pragma unroll
                    for (int k = 0; k < 15; ++k) s = fmaf(h[k], wl[k * 15 + j], s);
                    o[j] = s * di;
                }
                __half2 ob[8];
#pragma unroll
                for (int j = 0; j < 8; ++j)
                    ob[j] = __floats2half2_rn(o[2 * j], o[2 * j + 1]);
                *(int4*)((__half*)outp + (size_t)node * 16) = *(int4*)&ob[0];
                *(int4*)((__half*)outp + (size_t)node * 16 + 8) = *(int4*)&ob[4];
            } else {
                float o[4];
#pragma unroll
                for (int j = 0; j < 4; ++j) {
                    float s = 0.f;
#pragma unroll
                    for (int k = 0; k < 15; ++k) s = fmaf(h[k], wl[k * 4 + j], s);
                    o[j] = s * di;
                }
                __half2 ob[2];
                ob[0] = __floats2half2_rn(o[0], o[1]);
                ob[1] = __floats2half2_rn(o[2], o[3]);
                *(float2*)((__half*)outp + (size_t)node * 4) = *(float2*)&ob[0];
            }
        }
    }
}

extern "C" void kernel_launch(void* const* d_in, const int* in_sizes, int n_in,
                              void* d_out, int out_size, void* d_ws, size_t ws_size,
                              hipStream_t stream) {
    const float* x  = (const float*)d_in[0];
    const int*   ei = (const int*)d_in[1];
    const float* W1 = (const float*)d_in[3];
    const float* b1 = (const float*)d_in[4];
    const float* W2 = (const float*)d_in[5];
    const float* b2 = (const float*)d_in[6];
    const float* W3 = (const float*)d_in[7];
    const float* b3 = (const float*)d_in[8];
    float* out = (float*)d_out;

    const int N = in_sizes[0] / 15;
    const int E = in_sizes[1] / 2;
    const int* src = ei;
    const int* dst = ei + E;
    const int NBr = (N + BKN - 1) / BKN;   // live buckets (977)
    const int PB  = (NBr + 1) / 2;         // pull blocks (489)

    char* ws = (char*)d_ws;
    auto align = [](size_t v) { return (v + 255) & ~(size_t)255; };
    size_t off = 0;
    uint* rowp8 = (uint*)(ws + off); off += align((size_t)NPART * (1u << 19) * 4);
    float* dis  = (float*)(ws + off); off += align((size_t)N * 4);
    uint* gcur  = (uint*)(ws + off); off += align((size_t)NBMAX * 4);
    uint* bars  = (uint*)(ws + off); off += align((size_t)2 * BAR_LAYER * 4);
    int*  srcS  = (int*)(ws + off);  off += align((size_t)NBMAX * SCAP * 4);
    // slabY: bucketed (71MB) dead after k_csr, overlaid by B'(fp16)+C'(fp16)
    char* slabY = ws + off;
    uint*   bucketed = (uint*)slabY;
    __half* Bp = (__half*)slabY;
    __half* Cp = (__half*)(slabY + align((size_t)(N + 1) * 16 * 2));
    off += align((size_t)NBMAX * BCAP * 4);
    __half* Ap = (__half*)(ws + off);  // (N+1) x 16 fp16

    const int nTiles = (E + PT_TILE - 1) / PT_TILE;

    // CSR build (partition-major rows, fixed slabs) + fused layer-1 linear
    k_init<<<1, 1024, 0, stream>>>(gcur, bars);
    k_part<<<nTiles, PT_THREADS, 0, stream>>>(src, dst, E, gcur, bucketed);
    k_csr<<<NBr, 512, 0, stream>>>(bucketed, gcur, rowp8, dis, srcS, x, W1, Ap, N);
    // bucketed dead -> slabY becomes B'/C'

    // sentinel zero-rows (row N) for pad gathers
    hipMemsetAsync(Ap + (size_t)N * 16, 0, 16 * 2, stream);
    hipMemsetAsync(Bp + (size_t)N * 16, 0, 16 * 2, stream);
    hipMemsetAsync(Cp + (size_t)N * 4, 0, 4 * 2, stream);

    k_pull_res<1><<<PB, 512, 0, stream>>>(Ap, srcS, rowp8, dis, W2, b1, Bp,
                                          bars + 0 * BAR_LAYER, PB, N);
    k_pull_res<2><<<PB, 512, 0, stream>>>(Bp, srcS, rowp8, dis, W3, b2, Cp,
                                          bars + 1 * BAR_LAYER, PB, N);
    k_pull_res<3><<<PB, 512, 0, stream>>>(Cp, srcS, rowp8, dis, nullptr, b3, out,
                                          nullptr, PB, N);
}

// Round 16
// 781.586 us; speedup vs baseline: 1.0449x; 1.0082x over previous
//
#include <hip/hip_runtime.h>
#include <hip/hip_fp16.h>

// GCN 3-layer forward. R21 = R20's wave-structured scans + sentinel memsets
// restored to AFTER k_csr (R20 bug: Bp/Cp sentinels live in slabY, which
// k_part's bucketed writes clobber if zeroed early -> absmax 8.7e4).
//  - k_part/k_csr scans: per-wave __shfl_up + 8-entry wave-sum (1 barrier,
//    was 18) -- this is the change R20 failed to measure
//  - R19 rank-cached fill, R16 pad-2 pulls (closed at request-rate floor)
// Overlay lesson: dispatch reordering must re-verify aliased live ranges.

typedef unsigned int uint;
typedef unsigned short ushort;
typedef unsigned long long ull;

#define NBMAX 1024        // max buckets (dst >> 9), 512 nodes each
#define BKN 512
#define BCAP 17408        // bucketed slab cap per bucket (mean 16384, +8 sigma)
#define EPT 34            // bucketed entries per k_csr thread (BCAP/512)
#define SCAP 24576        // srcS slab cap (mean ~18.4k padded, huge headroom)
#define PT_THREADS 512
#define PT_TILE 8192      // 16 edges per thread
#define NPART 8           // src partitions (src>>16): 2MB fp16 table slices
#define BAR_STRIDE 528    // uints per barrier row (root + 32 spread counters)
#define BAR_LAYER (7 * BAR_STRIDE)

// ---- init: fixed slab cursors + barrier counters ----
__global__ void k_init(uint* __restrict__ gcur, uint* __restrict__ bars) {
    int t = threadIdx.x;                 // 1024 threads, 1 block
    gcur[t] = (uint)t * BCAP;
    for (int i = t; i < 2 * BAR_LAYER; i += 1024) bars[i] = 0;
}

// ---- LDS-staged partition: edges -> bucketed (packed src | dstLocal<<19) ----
__global__ __launch_bounds__(PT_THREADS) void k_part(const int* __restrict__ src,
                                                     const int* __restrict__ dst, int E,
                                                     uint* __restrict__ gcur,
                                                     uint* __restrict__ bucketed) {
    __shared__ uint stage[PT_TILE];
    __shared__ ushort sbuck[PT_TILE];
    __shared__ uint hist[NBMAX], lofs[NBMAX], base[NBMAX];
    __shared__ uint wsum[8];
    int t = threadIdx.x;
    long long start = (long long)blockIdx.x * PT_TILE;
    int cnt = (int)min((long long)PT_TILE, (long long)E - start);

    hist[2 * t] = 0; hist[2 * t + 1] = 0;
    __syncthreads();
    uint myb[16], myr[16], mys[16];
#pragma unroll
    for (int k = 0; k < 16; ++k) {
        int idx = t + k * PT_THREADS;
        if (idx < cnt) {
            uint d = (uint)dst[start + idx];
            uint s = (uint)src[start + idx];
            uint b = d >> 9;
            myb[k] = b;
            mys[k] = s | ((d & 511u) << 19);
            myr[k] = atomicAdd(&hist[b], 1u);
        }
    }
    __syncthreads();
    uint h0 = hist[2 * t], h1 = hist[2 * t + 1];
    uint v = h0 + h1;
    // wave-structured inclusive scan (no barriers inside)
    uint incl = v;
#pragma unroll
    for (int off = 1; off < 64; off <<= 1) {
        uint xv = __shfl_up(incl, off, 64);
        if ((t & 63) >= off) incl += xv;
    }
    if ((t & 63) == 63) wsum[t >> 6] = incl;
    __syncthreads();
    uint wpre = 0;
#pragma unroll
    for (int w = 0; w < 8; ++w) { uint s = wsum[w]; if (w < (t >> 6)) wpre += s; }
    uint ex = wpre + incl - v;
    lofs[2 * t] = ex;
    lofs[2 * t + 1] = ex + h0;
    if (h0) base[2 * t] = atomicAdd(&gcur[2 * t], h0);
    if (h1) base[2 * t + 1] = atomicAdd(&gcur[2 * t + 1], h1);
    __syncthreads();
#pragma unroll
    for (int k = 0; k < 16; ++k) {
        int idx = t + k * PT_THREADS;
        if (idx < cnt) {
            uint pos = lofs[myb[k]] + myr[k];
            stage[pos] = mys[k];
            sbuck[pos] = (ushort)myb[k];
        }
    }
    __syncthreads();
#pragma unroll
    for (int k = 0; k < 16; ++k) {
        int idx = t + k * PT_THREADS;
        if (idx < cnt) {
            uint b = sbuck[idx];
            uint pos = base[b] + ((uint)idx - lofs[b]);
            if (pos < (uint)(b + 1) * BCAP) bucketed[pos] = stage[idx];  // ~always
        }
    }
}

// ---- per-bucket CSR (counting sort, pad-to-2, rank-cached fill) + fused lin1 ----
// rowp8[(p<<19)+node] = (slabStart+segStart) | (cnt<<25); pad slots = sentinel N.
__global__ __launch_bounds__(512) void k_csr(const uint* __restrict__ bucketed,
                                             const uint* __restrict__ gcur,
                                             uint* __restrict__ rowp8,
                                             float* __restrict__ dis,
                                             int* __restrict__ srcS,
                                             const float* __restrict__ x,
                                             const float* __restrict__ W1,
                                             __half* __restrict__ Ap, int N) {
    __shared__ uint c[BKN * NPART];        // counts -> segment starts (reused)
    __shared__ uint wsum[8];
    __shared__ __align__(16) int stage[SCAP];
    int b = blockIdx.x, t = threadIdx.x;
    uint beg = (uint)b * BCAP;
    uint end = min(gcur[b], (uint)(b + 1) * BCAP);
    for (int i = t; i < BKN * NPART; i += 512) c[i] = 0;
    __syncthreads();
    uint reg[EPT];                         // static-indexed (full unroll) -> VGPRs
    ushort rk[EPT];                        // within-key rank from histogram pass
#pragma unroll
    for (int i = 0; i < EPT; ++i) {
        uint e = beg + (uint)t + (uint)i * 512u;
        bool ok = e < end;
        uint v = ok ? bucketed[e] : 0u;
        reg[i] = ok ? v : 0xffffffffu;     // sentinel = skip
        rk[i] = 0;
        if (ok) {
            uint key = (((v & 0x7ffffu) >> 16) << 9) | (v >> 19);
            rk[i] = (ushort)atomicAdd(&c[key], 1u);
        }
    }
    __syncthreads();
    // degree -> dis (before counts become starts); keep dival live for lin tail
    int node = (b << 9) + t;
    float dival = 0.f;
    if (node < N) {
        uint deg = 0;
#pragma unroll
        for (int p = 0; p < NPART; ++p) deg += c[(p << 9) | t];
        dival = rsqrtf((float)(deg + 1u));   // +1 self-loop
        dis[node] = dival;
    }
    // thread t owns keys 8t..8t+7 (one partition p=t>>6, 8 consecutive locals)
    uint cnt[8], pad[8], ps = 0;
#pragma unroll
    for (int i = 0; i < 8; ++i) {
        cnt[i] = c[t * 8 + i];
        pad[i] = (cnt[i] + 1u) & ~1u;       // pad-to-2
        ps += pad[i];
    }
    // wave-structured inclusive scan of ps (single barrier; also orders the
    // per-thread c-reads above against the c-writes below)
    uint incl = ps;
#pragma unroll
    for (int off = 1; off < 64; off <<= 1) {
        uint xv = __shfl_up(incl, off, 64);
        if ((t & 63) >= off) incl += xv;
    }
    if ((t & 63) == 63) wsum[t >> 6] = incl;
    __syncthreads();
    uint wpre = 0, tot = 0;
#pragma unroll
    for (int w = 0; w < 8; ++w) { uint s = wsum[w]; tot += s; if (w < (t >> 6)) wpre += s; }
    uint kb = wpre + incl - ps;
    uint slab = (uint)b * SCAP;
    int p = t >> 6, local0 = (t & 63) << 3;
    uint run = kb;
#pragma unroll
    for (int i = 0; i < 8; ++i) {
        uint st = run;
        rowp8[((uint)p << 19) + (uint)((b << 9) + local0 + i)] =
            (slab + st) | (cnt[i] << 25);
        c[t * 8 + i] = st;                  // segment start (no atomics in fill)
        if (cnt[i] & 1u) {                  // sentinel pad (<=1)
            uint idx = st + cnt[i];
            if (idx < (uint)SCAP) stage[idx] = N;
            else srcS[slab + idx] = N;      // ~never (spill)
        }
        run += pad[i];
    }
    __syncthreads();
#pragma unroll
    for (int i = 0; i < EPT; ++i) {
        uint v = reg[i];
        if (v != 0xffffffffu) {
            uint s = v & 0x7ffffu;
            uint key = ((s >> 16) << 9) | (v >> 19);
            uint idx = c[key] + (uint)rk[i];   // base + cached rank, atomic-free
            if (idx < (uint)SCAP) stage[idx] = (int)s;
            else srcS[slab + idx] = (int)s;    // ~never (spill)
        }
    }
    __syncthreads();
    uint capped = min(tot, (uint)SCAP);
    uint cap4 = capped & ~3u;
    for (uint i = t * 4; i < cap4; i += 512 * 4)
        *(int4*)(srcS + slab + i) = *(const int4*)(stage + i);
    if (t < (int)(capped & 3u)) srcS[slab + cap4 + t] = stage[cap4 + t];
    // ---- fused layer-1 linear (no LDS deps; W1 reads are wave-uniform) ----
    if (node < N) {
        float in[15];
#pragma unroll
        for (int j = 0; j < 15; ++j) in[j] = x[(size_t)node * 15 + j];
        float o[16];
        o[15] = 0.f;
#pragma unroll
        for (int oj = 0; oj < 15; ++oj) {
            float acc = 0.f;
#pragma unroll
            for (int j = 0; j < 15; ++j) acc = fmaf(in[j], W1[j * 15 + oj], acc);
            o[oj] = acc * dival;
        }
        __half2 ob[8];
#pragma unroll
        for (int j = 0; j < 8; ++j)
            ob[j] = __floats2half2_rn(o[2 * j], o[2 * j + 1]);
        *(int4*)(Ap + (size_t)node * 16) = *(int4*)&ob[0];
        *(int4*)(Ap + (size_t)node * 16 + 8) = *(int4*)&ob[4];
    }
}

// ---- soft global barrier: locality pacing only (no correctness dependence) ----
__device__ __forceinline__ void softbar(uint* __restrict__ bars, int phase, int nblk) {
    __syncthreads();
    if (threadIdx.x == 0) {
        uint* row = bars + phase * BAR_STRIDE;
        uint ngroups = ((uint)nblk + 31u) >> 5;
        uint g = (uint)blockIdx.x >> 5;
        uint gsz = min(32u, (uint)nblk - g * 32u);
        uint prev = atomicAdd(&row[16 + g * 16], 1u);   // spread counters, own line
        if (prev + 1u == gsz) atomicAdd(&row[0], 1u);
        int spins = 0;
        while (spins < 2000) {
            uint v = __hip_atomic_load(&row[0], __ATOMIC_RELAXED,
                                       __HIP_MEMORY_SCOPE_AGENT);
            if (v >= ngroups) break;
            __builtin_amdgcn_s_sleep(8);
            ++spins;
        }
    }
    __syncthreads();
}

template <int TW>
__device__ __forceinline__ void load_row(const __half* __restrict__ tab, int node,
                                         float (&acc)[TW]) {
    if constexpr (TW == 16) {
        int4 w0 = *(const int4*)(tab + (size_t)node * 16);
        int4 w1 = *(const int4*)(tab + (size_t)node * 16 + 8);
        const __half2* h0 = (const __half2*)&w0;
        const __half2* h1 = (const __half2*)&w1;
#pragma unroll
        for (int u = 0; u < 4; ++u) {
            float2 f0 = __half22float2(h0[u]);
            float2 f1 = __half22float2(h1[u]);
            acc[2 * u] = f0.x;
            acc[2 * u + 1] = f0.y;
            acc[8 + 2 * u] = f1.x;
            acc[8 + 2 * u + 1] = f1.y;
        }
    } else {
        int2 w = *(const int2*)(tab + (size_t)node * 4);
        const __half2* h = (const __half2*)&w;
        float2 f0 = __half22float2(h[0]);
        float2 f1 = __half22float2(h[1]);
        acc[0] = f0.x; acc[1] = f0.y; acc[2] = f1.x; acc[3] = f1.y;
    }
}

// gather, 2 rows per iter (pad-to-2): 32B rows as 2x dwordx4, 8B as dwordx2
template <int TW>
__device__ __forceinline__ void gather_seg(const __half* __restrict__ tab,
                                           const int* __restrict__ srcS,
                                           uint rv, float (&acc)[TW]) {
    uint cnt = rv >> 25;
    if (!cnt) return;
    uint e = rv & 0x1ffffffu;
    uint end2 = e + ((cnt + 1u) & ~1u);
    for (; e < end2; e += 2) {
        ull w = *(const ull*)(srcS + e);        // 8B-aligned segment
        int s0 = (int)(uint)(w & 0xffffffffull);
        int s1 = (int)(uint)(w >> 32);
        if constexpr (TW == 16) {
            const int4* p0 = (const int4*)(tab + (size_t)s0 * 16);
            const int4* p1 = (const int4*)(tab + (size_t)s1 * 16);
            int4 r[4];
            r[0] = p0[0]; r[1] = p1[0]; r[2] = p0[1]; r[3] = p1[1];
#pragma unroll
            for (int q = 0; q < 4; ++q) {
                const __half2* h2 = (const __half2*)&r[q];
                int base = (q >> 1) * 8;        // r[0..1] -> lo half, r[2..3] -> hi
#pragma unroll
                for (int u = 0; u < 4; ++u) {
                    float2 f = __half22float2(h2[u]);
                    acc[base + 2 * u] += f.x;
                    acc[base + 2 * u + 1] += f.y;
                }
            }
        } else {                                // TW == 4
            int2 r0 = *(const int2*)(tab + (size_t)s0 * 4);
            int2 r1 = *(const int2*)(tab + (size_t)s1 * 4);
            const __half2* h0 = (const __half2*)&r0;
            const __half2* h1 = (const __half2*)&r1;
#pragma unroll
            for (int u = 0; u < 2; ++u) {
                float2 f0 = __half22float2(h0[u]);
                float2 f1 = __half22float2(h1[u]);
                acc[2 * u] += f0.x + f1.x;
                acc[2 * u + 1] += f0.y + f1.y;
            }
        }
    }
}

// ---- resident phased pull: thread owns 2 nodes, register acc, 8 phases ----
// L=1: Ap->relu@W2->Bp  L=2: Bp->relu@W3->Cp  L=3: Cp->out fp32 (no softbar)
template <int L>
__global__ __launch_bounds__(512, 4) void k_pull_res(
    const __half* __restrict__ tab, const int* __restrict__ srcS,
    const uint* __restrict__ rowp8, const float* __restrict__ dis,
    const float* __restrict__ Wm, const float* __restrict__ bias,
    void* __restrict__ outp, uint* __restrict__ bars, int nblk, int N) {
    constexpr int TW = (L == 3) ? 4 : 16;
    __shared__ float wl[240];
    int t = threadIdx.x;
    int n0 = (blockIdx.x << 10) + t;
    int n1 = n0 + 512;
    if constexpr (L == 1) {
        for (int i = t; i < 225; i += 512) wl[i] = Wm[i];
        if (t < 15) wl[225 + t] = bias[t];
    }
    if constexpr (L == 2) {
        for (int i = t; i < 60; i += 512) wl[i] = Wm[i];
        if (t < 15) wl[60 + t] = bias[t];
    }
    if constexpr (L == 3) {
        if (t < 4) wl[t] = bias[t];
    }
    __syncthreads();
    bool v0 = n0 < N, v1 = n1 < N;
    float a0[TW], a1[TW];
    if (v0) load_row<TW>(tab, n0, a0);
    if (v1) load_row<TW>(tab, n1, a1);
    uint rv0 = v0 ? rowp8[(uint)n0] : 0u;      // phase-0 descriptors
    uint rv1 = v1 ? rowp8[(uint)n1] : 0u;
    for (int p = 0; p < NPART; ++p) {
        uint nv0 = 0u, nv1 = 0u;
        if (p < NPART - 1) {                   // prefetch next phase descriptors
            uint pb = (uint)(p + 1) << 19;
            if (v0) nv0 = rowp8[pb + (uint)n0];
            if (v1) nv1 = rowp8[pb + (uint)n1];
        }
        if (v0) gather_seg<TW>(tab, srcS, rv0, a0);
        if (v1) gather_seg<TW>(tab, srcS, rv1, a1);
        if constexpr (L != 3) {                // pull3: 4MB table, locality moot
            if (p < NPART - 1) softbar(bars, p, nblk);
        }
        rv0 = nv0; rv1 = nv1;
    }
    // epilogue (per node, all-register MLP)
#pragma unroll
    for (int nn = 0; nn < 2; ++nn) {
        int node = nn ? n1 : n0;
        if (node >= N) continue;
        float* a = nn ? a1 : a0;
        float di = dis[node];
        if constexpr (L == 3) {
            float4 o;
            o.x = a[0] * di + wl[0];
            o.y = a[1] * di + wl[1];
            o.z = a[2] * di + wl[2];
            o.w = a[3] * di + wl[3];
            *(float4*)((float*)outp + (size_t)node * 4) = o;
        } else {
            float h[15];
#pragma unroll
            for (int j = 0; j < 15; ++j) {
                float bj = (L == 1) ? wl[225 + j] : wl[60 + j];
                h[j] = fmaxf(a[j] * di + bj, 0.f);
            }
            if constexpr (L == 1) {
                float o[16];
                o[15] = 0.f;
#pragma unroll
                for (int j = 0; j < 15; ++j) {
                    float s = 0.f;
#pragma unroll
                    for (int k = 0; k < 15; ++k) s = fmaf(h[k], wl[k * 15 + j], s);
                    o[j] = s * di;
                }
                __half2 ob[8];
#pragma unroll
                for (int j = 0; j < 8; ++j)
                    ob[j] = __floats2half2_rn(o[2 * j], o[2 * j + 1]);
                *(int4*)((__half*)outp + (size_t)node * 16) = *(int4*)&ob[0];
                *(int4*)((__half*)outp + (size_t)node * 16 + 8) = *(int4*)&ob[4];
            } else {
                float o[4];
#pragma unroll
                for (int j = 0; j < 4; ++j) {
                    float s = 0.f;
#pragma unroll
                    for (int k = 0; k < 15; ++k) s = fmaf(h[k], wl[k * 4 + j], s);
                    o[j] = s * di;
                }
                __half2 ob[2];
                ob[0] = __floats2half2_rn(o[0], o[1]);
                ob[1] = __floats2half2_rn(o[2], o[3]);
                *(float2*)((__half*)outp + (size_t)node * 4) = *(float2*)&ob[0];
            }
        }
    }
}

extern "C" void kernel_launch(void* const* d_in, const int* in_sizes, int n_in,
                              void* d_out, int out_size, void* d_ws, size_t ws_size,
                              hipStream_t stream) {
    const float* x  = (const float*)d_in[0];
    const int*   ei = (const int*)d_in[1];
    const float* W1 = (const float*)d_in[3];
    const float* b1 = (const float*)d_in[4];
    const float* W2 = (const float*)d_in[5];
    const float* b2 = (const float*)d_in[6];
    const float* W3 = (const float*)d_in[7];
    const float* b3 = (const float*)d_in[8];
    float* out = (float*)d_out;

    const int N = in_sizes[0] / 15;
    const int E = in_sizes[1] / 2;
    const int* src = ei;
    const int* dst = ei + E;
    const int NBr = (N + BKN - 1) / BKN;   // live buckets (977)
    const int PB  = (NBr + 1) / 2;         // pull blocks (489)

    char* ws = (char*)d_ws;
    auto align = [](size_t v) { return (v + 255) & ~(size_t)255; };
    size_t off = 0;
    uint* rowp8 = (uint*)(ws + off); off += align((size_t)NPART * (1u << 19) * 4);
    float* dis  = (float*)(ws + off); off += align((size_t)N * 4);
    uint* gcur  = (uint*)(ws + off); off += align((size_t)NBMAX * 4);
    uint* bars  = (uint*)(ws + off); off += align((size_t)2 * BAR_LAYER * 4);
    int*  srcS  = (int*)(ws + off);  off += align((size_t)NBMAX * SCAP * 4);
    // slabY: bucketed (71MB) dead after k_csr, overlaid by B'(fp16)+C'(fp16)
    char* slabY = ws + off;
    uint*   bucketed = (uint*)slabY;
    __half* Bp = (__half*)slabY;
    __half* Cp = (__half*)(slabY + align((size_t)(N + 1) * 16 * 2));
    off += align((size_t)NBMAX * BCAP * 4);
    __half* Ap = (__half*)(ws + off);  // (N+1) x 16 fp16

    const int nTiles = (E + PT_TILE - 1) / PT_TILE;

    // CSR build (partition-major rows, fixed slabs) + fused layer-1 linear
    k_init<<<1, 1024, 0, stream>>>(gcur, bars);
    k_part<<<nTiles, PT_THREADS, 0, stream>>>(src, dst, E, gcur, bucketed);
    k_csr<<<NBr, 512, 0, stream>>>(bucketed, gcur, rowp8, dis, srcS, x, W1, Ap, N);
    // bucketed dead -> slabY becomes B'/C'; sentinels must be zeroed HERE
    hipMemsetAsync(Ap + (size_t)N * 16, 0, 16 * 2, stream);
    hipMemsetAsync(Bp + (size_t)N * 16, 0, 16 * 2, stream);
    hipMemsetAsync(Cp + (size_t)N * 4, 0, 4 * 2, stream);

    k_pull_res<1><<<PB, 512, 0, stream>>>(Ap, srcS, rowp8, dis, W2, b1, Bp,
                                          bars + 0 * BAR_LAYER, PB, N);
    k_pull_res<2><<<PB, 512, 0, stream>>>(Bp, srcS, rowp8, dis, W3, b2, Cp,
                                          bars + 1 * BAR_LAYER, PB, N);
    k_pull_res<3><<<PB, 512, 0, stream>>>(Cp, srcS, rowp8, dis, nullptr, b3, out,
                                          nullptr, PB, N);
}